// Round 3
// baseline (691.557 us; speedup 1.0000x reference)
//
#include <hip/hip_runtime.h>
#include <stdint.h>

// GAT encoder: 3 GAT layers + masked global max pool.
// N=20000 nodes, E=320000 edges (+N self loops), B=16 batches.
// Round-3 finding: float tensors are FP32 (not bf16) and output is FP32.
// Full fp32 pipeline; ws use ~84 MB.

#define NN 20000
#define NE 320000
#define NBATCH 16
#define NEG 0.2f

static __device__ __forceinline__ unsigned encf(float f) {
  unsigned u = __float_as_uint(f);
  return (u & 0x80000000u) ? ~u : (u | 0x80000000u);
}
static __device__ __forceinline__ float decf(unsigned u) {
  return __uint_as_float((u & 0x80000000u) ? (u ^ 0x80000000u) : ~u);
}

// ---------------- init + CSR build ----------------
__global__ void k_init(int* deg, unsigned* enc, int* flag) {
  int i = blockIdx.x * blockDim.x + threadIdx.x;
  if (i < NN) deg[i] = 1;  // self loop
  if (i < NBATCH * 128) enc[i] = ~__float_as_uint(-1e30f);  // encf(-1e30)
  if (i == 0) *flag = 0;
}

__global__ void k_count(const int* __restrict__ ei, int* __restrict__ deg) {
  int e = blockIdx.x * blockDim.x + threadIdx.x;
  if (e < NE) atomicAdd(&deg[ei[NE + e]], 1);
}

__global__ void k_scan(const int* __restrict__ deg, int* __restrict__ row_ptr,
                       int* __restrict__ cursor) {
  __shared__ int sums[1024];
  int t = threadIdx.x;
  const int CH = (NN + 1023) / 1024;  // 20
  int beg = t * CH, end = min(NN, beg + CH);
  int s = 0;
  for (int i = beg; i < end; i++) s += deg[i];
  sums[t] = s;
  __syncthreads();
  for (int off = 1; off < 1024; off <<= 1) {
    int v = sums[t];
    int add = (t >= off) ? sums[t - off] : 0;
    __syncthreads();
    sums[t] = v + add;
    __syncthreads();
  }
  int run = (t == 0) ? 0 : sums[t - 1];
  for (int i = beg; i < end; i++) {
    row_ptr[i] = run;
    cursor[i] = run;
    run += deg[i];
  }
  if (t == 1023) row_ptr[NN] = run;
}

__global__ void k_fill(const int* __restrict__ ei, int* __restrict__ cursor,
                       int* __restrict__ col) {
  int i = blockIdx.x * blockDim.x + threadIdx.x;
  if (i >= NE + NN) return;
  int src, dst;
  if (i < NE) { src = ei[i]; dst = ei[NE + i]; }
  else        { src = dst = i - NE; }
  int pos = atomicAdd(&cursor[dst], 1);
  col[pos] = src;
}

// ---------------- GEMM: fp32 A @ fp32 B -> fp32 C ----------------
__global__ __launch_bounds__(256) void k_gemm(const float* __restrict__ A,
                                              const float* __restrict__ Bw,
                                              float* __restrict__ C, int M, int K,
                                              int Nc) {
  __shared__ float As[16][68];  // [k][m]; 68*4=272B=17*16 -> rows stay 16B-aligned
  __shared__ float Bs[16][68];  // [k][n]
  int bm = blockIdx.y * 64, bn = blockIdx.x * 64;
  int tid = threadIdx.x;
  int lm = tid >> 2, lk = (tid & 3) * 4;     // A tile load
  int lbk = tid >> 4, lbn = (tid & 15) * 4;  // B tile load
  int tr = tid >> 4, tc = tid & 15;          // compute: 16x16 threads, 4x4 each
  float acc[4][4] = {};
  for (int k0 = 0; k0 < K; k0 += 16) {
    int arow = bm + lm;
    float4 av = make_float4(0.f, 0.f, 0.f, 0.f);
    if (arow < M) av = *(const float4*)(A + (size_t)arow * K + k0 + lk);
    As[lk + 0][lm] = av.x;
    As[lk + 1][lm] = av.y;
    As[lk + 2][lm] = av.z;
    As[lk + 3][lm] = av.w;
    float4 bv = *(const float4*)(Bw + (size_t)(k0 + lbk) * Nc + bn + lbn);
    *(float4*)&Bs[lbk][lbn] = bv;
    __syncthreads();
#pragma unroll
    for (int kk = 0; kk < 16; kk++) {
      float a0 = As[kk][tr * 4 + 0], a1 = As[kk][tr * 4 + 1];
      float a2 = As[kk][tr * 4 + 2], a3 = As[kk][tr * 4 + 3];
      float b0 = Bs[kk][tc * 4 + 0], b1 = Bs[kk][tc * 4 + 1];
      float b2 = Bs[kk][tc * 4 + 2], b3 = Bs[kk][tc * 4 + 3];
      acc[0][0] += a0 * b0; acc[0][1] += a0 * b1; acc[0][2] += a0 * b2; acc[0][3] += a0 * b3;
      acc[1][0] += a1 * b0; acc[1][1] += a1 * b1; acc[1][2] += a1 * b2; acc[1][3] += a1 * b3;
      acc[2][0] += a2 * b0; acc[2][1] += a2 * b1; acc[2][2] += a2 * b2; acc[2][3] += a2 * b3;
      acc[3][0] += a3 * b0; acc[3][1] += a3 * b1; acc[3][2] += a3 * b2; acc[3][3] += a3 * b3;
    }
    __syncthreads();
  }
#pragma unroll
  for (int i = 0; i < 4; i++) {
    int row = bm + tr * 4 + i;
    if (row < M) {
      float* cp = C + (size_t)row * Nc + bn + tc * 4;
      cp[0] = acc[i][0]; cp[1] = acc[i][1]; cp[2] = acc[i][2]; cp[3] = acc[i][3];
    }
  }
}

// ---------------- alpha_src / alpha_dst per node (one wave per node) --------
template <int H>
__global__ void k_alpha(const float* __restrict__ h, const float* __restrict__ atts,
                        const float* __restrict__ attd, float* __restrict__ as_,
                        float* __restrict__ ad_) {
  int gid = blockIdx.x * blockDim.x + threadIdx.x;
  int node = gid >> 6, lane = gid & 63;
  if (node >= NN) return;
  constexpr int HF = H * 128, PL = HF / 64, G = 64 / H;
  const float* hp = h + (size_t)node * HF + lane * PL;
  float ps = 0.f, pd = 0.f;
#pragma unroll
  for (int i = 0; i < PL; i++) {
    int idx = lane * PL + i;
    float hv = hp[i];
    ps += hv * atts[idx];
    pd += hv * attd[idx];
  }
#pragma unroll
  for (int off = G >> 1; off; off >>= 1) {
    ps += __shfl_xor(ps, off, 64);
    pd += __shfl_xor(pd, off, 64);
  }
  if ((lane & (G - 1)) == 0) {
    int hh = lane / G;
    as_[node * H + hh] = ps;
    ad_[node * H + hh] = pd;
  }
}

// ---------------- softmax + aggregate (one wave per dst node) ----------------
template <int H, bool RELU>
__global__ __launch_bounds__(256) void k_agg(const float* __restrict__ h,
                                             const float* __restrict__ as_,
                                             const float* __restrict__ ad_,
                                             const int* __restrict__ row_ptr,
                                             const int* __restrict__ col,
                                             const float* __restrict__ bias,
                                             float* __restrict__ out) {
  int gid = blockIdx.x * blockDim.x + threadIdx.x;
  int node = gid >> 6, lane = gid & 63;
  if (node >= NN) return;
  constexpr int HF = H * 128, PL = HF / 64;
  int beg = row_ptr[node], end = row_ptr[node + 1];
  float adv[H], m[H], sum[H];
#pragma unroll
  for (int hh = 0; hh < H; hh++) {
    adv[hh] = ad_[node * H + hh];
    m[hh] = -1e30f;
    sum[hh] = 0.f;
  }
  // pass 1: per-head max of leaky_relu(alpha_s[src]+alpha_d[dst])
  for (int j = beg + lane; j < end; j += 64) {
    int s = col[j];
#pragma unroll
    for (int hh = 0; hh < H; hh++) {
      float e = as_[s * H + hh] + adv[hh];
      e = (e > 0.f) ? e : NEG * e;
      m[hh] = fmaxf(m[hh], e);
    }
  }
#pragma unroll
  for (int hh = 0; hh < H; hh++)
#pragma unroll
    for (int off = 32; off; off >>= 1) m[hh] = fmaxf(m[hh], __shfl_xor(m[hh], off, 64));
  // pass 2: denom
  for (int j = beg + lane; j < end; j += 64) {
    int s = col[j];
#pragma unroll
    for (int hh = 0; hh < H; hh++) {
      float e = as_[s * H + hh] + adv[hh];
      e = (e > 0.f) ? e : NEG * e;
      sum[hh] += __expf(e - m[hh]);
    }
  }
#pragma unroll
  for (int hh = 0; hh < H; hh++)
#pragma unroll
    for (int off = 32; off; off >>= 1) sum[hh] += __shfl_xor(sum[hh], off, 64);
  // pass 3: weighted accumulate of h[src] (fp32 gather, 32B/lane for H=4)
  int fbase = lane * PL;
  int myh = fbase >> 7;
  float mym = m[myh], myinv = 1.f / sum[myh], myad = adv[myh];
  float acc[PL] = {};
  for (int j = beg; j < end; ++j) {
    int s = col[j];
    float e = as_[s * H + myh] + myad;
    e = (e > 0.f) ? e : NEG * e;
    float w = __expf(e - mym) * myinv;
    const float* hp = h + (size_t)s * HF + fbase;
    if constexpr (PL == 8) {
      float4 v0 = *(const float4*)hp;
      float4 v1 = *(const float4*)(hp + 4);
      acc[0] += w * v0.x; acc[1] += w * v0.y; acc[2] += w * v0.z; acc[3] += w * v0.w;
      acc[4] += w * v1.x; acc[5] += w * v1.y; acc[6] += w * v1.z; acc[7] += w * v1.w;
    } else {
      float2 v = *(const float2*)hp;
      acc[0] += w * v.x; acc[1] += w * v.y;
    }
  }
  float* op = out + (size_t)node * HF + fbase;
#pragma unroll
  for (int i = 0; i < PL; i++) {
    float v = acc[i] + bias[fbase + i];
    if (RELU) v = fmaxf(v, 0.f);
    op[i] = v;
  }
}

// ---------------- masked global max pool ----------------
__global__ void k_mask_any(const int* __restrict__ mask, int* __restrict__ flag) {
  int i = blockIdx.x * blockDim.x + threadIdx.x;
  if (i < NN && mask[i] != 0) *flag = 1;
}

__global__ void k_pool(const float* __restrict__ h, const int* __restrict__ batch,
                       const int* __restrict__ mask, const int* __restrict__ flag,
                       unsigned* __restrict__ enc) {
  int f = threadIdx.x;  // 128 threads = 128 features
  int n0 = blockIdx.x * 32;
  if (n0 >= NN) return;
  int n1 = min(NN, n0 + 32);
  int any = *flag;
  float local = -1e30f;
  int curb = batch[n0];
  for (int n = n0; n < n1; ++n) {
    int b = batch[n];
    if (b != curb) {
      if (local > -1e30f) atomicMax(&enc[curb * 128 + f], encf(local));
      local = -1e30f;
      curb = b;
    }
    bool valid = (mask[n] == 0) || (!any);
    if (valid) local = fmaxf(local, h[(size_t)n * 128 + f]);
  }
  if (local > -1e30f) atomicMax(&enc[curb * 128 + f], encf(local));
}

__global__ void k_out(const unsigned* __restrict__ enc, float* __restrict__ out) {
  int i = blockIdx.x * blockDim.x + threadIdx.x;
  if (i < NBATCH * 128) out[i] = decf(enc[i]);  // unwritten slots -> exactly -1e30f
}

extern "C" void kernel_launch(void* const* d_in, const int* in_sizes, int n_in,
                              void* d_out, int out_size, void* d_ws, size_t ws_size,
                              hipStream_t stream) {
  const float* x = (const float*)d_in[0];
  const int* ei = (const int*)d_in[1];
  const int* batch = (const int*)d_in[2];
  const int* nmask = (const int*)d_in[3];
  // d_in[4] = edge_mask, unused (edge_dim=None in reference)
  const float* W1 = (const float*)d_in[5];
  const float* as1 = (const float*)d_in[6];
  const float* ad1 = (const float*)d_in[7];
  const float* b1 = (const float*)d_in[8];
  const float* W2 = (const float*)d_in[9];
  const float* as2 = (const float*)d_in[10];
  const float* ad2 = (const float*)d_in[11];
  const float* b2 = (const float*)d_in[12];
  const float* W3 = (const float*)d_in[13];
  const float* as3 = (const float*)d_in[14];
  const float* ad3 = (const float*)d_in[15];
  const float* b3 = (const float*)d_in[16];

  char* ws = (char*)d_ws;
  size_t off = 0;
  auto alloc = [&](size_t bytes) -> char* {
    char* p = ws + off;
    off = (off + bytes + 255) & ~(size_t)255;
    return p;
  };
  float* hA = (float*)alloc((size_t)NN * 512 * 4);  // 41 MB
  float* hB = (float*)alloc((size_t)NN * 512 * 4);  // 41 MB
  float* alS = (float*)alloc((size_t)NN * 4 * 4);
  float* alD = (float*)alloc((size_t)NN * 4 * 4);
  int* deg = (int*)alloc((size_t)NN * 4);
  int* cursor = (int*)alloc((size_t)NN * 4);
  int* rowp = (int*)alloc((size_t)(NN + 1) * 4);
  int* colx = (int*)alloc((size_t)(NE + NN) * 4);
  unsigned* enc = (unsigned*)alloc((size_t)NBATCH * 128 * 4);
  int* flag = (int*)alloc(4);
  (void)ws_size; (void)n_in; (void)in_sizes; (void)out_size;

  // CSR by dst (reused by all 3 layers)
  k_init<<<(NN + 255) / 256, 256, 0, stream>>>(deg, enc, flag);
  k_count<<<(NE + 255) / 256, 256, 0, stream>>>(ei, deg);
  k_scan<<<1, 1024, 0, stream>>>(deg, rowp, cursor);
  k_fill<<<(NE + NN + 255) / 256, 256, 0, stream>>>(ei, cursor, colx);

  const int aggBlocks = (NN * 64) / 256;  // one wave per node
  dim3 g1(512 / 64, (NN + 63) / 64);
  dim3 g3(128 / 64, (NN + 63) / 64);

  // Layer 1
  k_gemm<<<g1, 256, 0, stream>>>(x, W1, hA, NN, 128, 512);
  k_alpha<4><<<aggBlocks, 256, 0, stream>>>(hA, as1, ad1, alS, alD);
  k_agg<4, true><<<aggBlocks, 256, 0, stream>>>(hA, alS, alD, rowp, colx, b1, hB);
  // Layer 2
  k_gemm<<<g1, 256, 0, stream>>>(hB, W2, hA, NN, 512, 512);
  k_alpha<4><<<aggBlocks, 256, 0, stream>>>(hA, as2, ad2, alS, alD);
  k_agg<4, true><<<aggBlocks, 256, 0, stream>>>(hA, alS, alD, rowp, colx, b2, hB);
  // Layer 3
  k_gemm<<<g3, 256, 0, stream>>>(hB, W3, hA, NN, 512, 128);
  k_alpha<1><<<aggBlocks, 256, 0, stream>>>(hA, as3, ad3, alS, alD);
  k_agg<1, false><<<aggBlocks, 256, 0, stream>>>(hA, alS, alD, rowp, colx, b3, hB);

  // Masked global max pool
  k_mask_any<<<(NN + 255) / 256, 256, 0, stream>>>(nmask, flag);
  k_pool<<<(NN + 31) / 32, 128, 0, stream>>>(hB, batch, nmask, flag, enc);
  k_out<<<(NBATCH * 128 + 255) / 256, 256, 0, stream>>>(enc, (float*)d_out);
}

// Round 4
// 621.585 us; speedup vs baseline: 1.1126x; 1.1126x over previous
//
#include <hip/hip_runtime.h>
#include <stdint.h>

// GAT encoder: 3 GAT layers + masked global max pool. fp32 pipeline.
// GEMMs run on the bf16 matrix pipe via bf16x6 error-compensated split
// (hi/mid trunc + lo RNE; 6 cross-term MFMAs -> fp32-equivalent accuracy).

#define NN 20000
#define NE 320000
#define NBATCH 16
#define NEG 0.2f

using bf16x8 = __attribute__((ext_vector_type(8))) __bf16;
using f32x4 = __attribute__((ext_vector_type(4))) float;

static __device__ __forceinline__ unsigned short f2bf(float f) {  // RNE
  unsigned u = __float_as_uint(f);
  return (unsigned short)((u + 0x7FFFu + ((u >> 16) & 1u)) >> 16);
}
static __device__ __forceinline__ unsigned encf(float f) {
  unsigned u = __float_as_uint(f);
  return (u & 0x80000000u) ? ~u : (u | 0x80000000u);
}
static __device__ __forceinline__ float decf(unsigned u) {
  return __uint_as_float((u & 0x80000000u) ? (u ^ 0x80000000u) : ~u);
}

struct S3 { unsigned short h, m, l; };
static __device__ __forceinline__ S3 split3(float a) {
  unsigned u = __float_as_uint(a);
  unsigned hi = u & 0xFFFF0000u;
  float r = a - __uint_as_float(hi);          // exact
  unsigned ur = __float_as_uint(r);
  unsigned mi = ur & 0xFFFF0000u;
  float r2 = r - __uint_as_float(mi);         // exact
  S3 o;
  o.h = (unsigned short)(hi >> 16);
  o.m = (unsigned short)(mi >> 16);
  o.l = f2bf(r2);
  return o;
}

// ---------------- init + CSR build ----------------
__global__ void k_init(int* deg, unsigned* enc) {
  int i = blockIdx.x * blockDim.x + threadIdx.x;
  if (i < NN) deg[i] = 1;  // self loop
  if (i < NBATCH * 128) enc[i] = ~__float_as_uint(-1e30f);  // encf(-1e30)
}

__global__ void k_count(const int* __restrict__ ei, int* __restrict__ deg) {
  int e = blockIdx.x * blockDim.x + threadIdx.x;
  if (e < NE) atomicAdd(&deg[ei[NE + e]], 1);
}

__global__ void k_scan(const int* __restrict__ deg, int* __restrict__ row_ptr,
                       int* __restrict__ cursor) {
  __shared__ int wsum[16];
  int t = threadIdx.x;  // 1024 threads
  int lane = t & 63, wid = t >> 6;
  const int CH = 20;
  int beg = t * CH;
  int s = 0;
  for (int i = 0; i < CH; i++) {
    int idx = beg + i;
    if (idx < NN) s += deg[idx];
  }
  int incl = s;
  for (int off = 1; off < 64; off <<= 1) {
    int v = __shfl_up(incl, off, 64);
    if (lane >= off) incl += v;
  }
  if (lane == 63) wsum[wid] = incl;
  __syncthreads();
  if (t < 16) {
    int v = wsum[t];
    int in2 = v;
    for (int off = 1; off < 16; off <<= 1) {
      int u = __shfl_up(in2, off, 16);
      if (t >= off) in2 += u;
    }
    wsum[t] = in2 - v;  // exclusive wave base
  }
  __syncthreads();
  int run = wsum[wid] + incl - s;  // exclusive prefix for this thread
  for (int i = 0; i < CH; i++) {
    int idx = beg + i;
    if (idx < NN) {
      row_ptr[idx] = run;
      cursor[idx] = run;
      run += deg[idx];
    }
  }
  if (t == 1023) row_ptr[NN] = run;
}

__global__ void k_fill(const int* __restrict__ ei, int* __restrict__ cursor,
                       int* __restrict__ col, const int* __restrict__ nmask,
                       int* __restrict__ flag) {
  int i = blockIdx.x * blockDim.x + threadIdx.x;
  if (i >= NE + NN) return;
  int src, dst;
  if (i < NE) {
    src = ei[i];
    dst = ei[NE + i];
  } else {
    src = dst = i - NE;
    if (nmask[src] != 0) *flag = 1;  // flag pre-zeroed by memsetAsync
  }
  int pos = atomicAdd(&cursor[dst], 1);
  col[pos] = src;
}

// ---------------- W prep: transpose + bf16x3 split ----------------
// in:  W  [K][Nc] fp32 row-major
// out: wt [3][Nc][K] bf16 (hi, mid, lo planes; [n][k] k-contiguous)
__global__ void k_wprep(const float* __restrict__ W, unsigned short* __restrict__ wt,
                        int K, int Nc, int ncshift) {
  int idx = blockIdx.x * blockDim.x + threadIdx.x;
  int n = idx & (Nc - 1);
  int k = idx >> ncshift;
  float a = W[(size_t)k * Nc + n];
  S3 s = split3(a);
  size_t pw = (size_t)Nc * K;
  size_t o = (size_t)n * K + k;
  wt[o] = s.h;
  wt[pw + o] = s.m;
  wt[2 * pw + o] = s.l;
}

// ---------------- GEMM: fp32 A @ fp32 W -> fp32 C via bf16x6 MFMA ----------
// Block 256 thr = 4 waves (2x2 of 64x64), tile 128x128, BK=32.
#define BM 128
#define BN 128
#define BK 32

__global__ __launch_bounds__(256, 2) void k_gemm(const float* __restrict__ A,
                                                 const unsigned short* __restrict__ Wt,
                                                 float* __restrict__ C, int M, int K,
                                                 int Nc) {
  __shared__ __align__(16) unsigned short As[3][BM][BK];  // 24 KB
  __shared__ __align__(16) unsigned short Bs[3][BN][BK];  // 24 KB
  int tid = threadIdx.x;
  int bm = blockIdx.y * BM, bn = blockIdx.x * BN;
  int wid = tid >> 6, lane = tid & 63;
  int wm = (wid >> 1) * 64, wn = (wid & 1) * 64;
  int lrow = lane & 15, lquad = lane >> 4;
  size_t planeW = (size_t)Nc * K;

  f32x4 acc[4][4] = {};

  for (int k0 = 0; k0 < K; k0 += BK) {
    __syncthreads();
    // stage A: 128x32 fp32 -> 3 bf16 planes (in-register split)
#pragma unroll
    for (int i = 0; i < 4; i++) {
      int slot = tid + 256 * i;          // 1024 float4 slots
      int row = slot >> 3;
      int kf = (slot & 7) * 4;
      int arow = bm + row;
      arow = arow < M ? arow : M - 1;
      float4 v = *(const float4*)(A + (size_t)arow * K + k0 + kf);
      S3 s0 = split3(v.x), s1 = split3(v.y), s2 = split3(v.z), s3 = split3(v.w);
      *(ushort4*)&As[0][row][kf] = make_ushort4(s0.h, s1.h, s2.h, s3.h);
      *(ushort4*)&As[1][row][kf] = make_ushort4(s0.m, s1.m, s2.m, s3.m);
      *(ushort4*)&As[2][row][kf] = make_ushort4(s0.l, s1.l, s2.l, s3.l);
    }
    // stage B: pre-split planes, straight copy
#pragma unroll
    for (int p = 0; p < 3; p++)
#pragma unroll
      for (int i = 0; i < 2; i++) {
        int slot = tid + 256 * i;        // 512 uint4 slots per plane
        int row = slot >> 2;
        int ks = (slot & 3) * 8;
        uint4 v = *(const uint4*)(Wt + (size_t)p * planeW + (size_t)(bn + row) * K +
                                  k0 + ks);
        *(uint4*)&Bs[p][row][ks] = v;
      }
    __syncthreads();

    bf16x8 af[3][4];
#pragma unroll
    for (int p = 0; p < 3; p++)
#pragma unroll
      for (int mf = 0; mf < 4; mf++)
        af[p][mf] = *(const bf16x8*)&As[p][wm + mf * 16 + lrow][lquad * 8];
#pragma unroll
    for (int nf = 0; nf < 4; nf++) {
      bf16x8 b0 = *(const bf16x8*)&Bs[0][wn + nf * 16 + lrow][lquad * 8];
      bf16x8 b1 = *(const bf16x8*)&Bs[1][wn + nf * 16 + lrow][lquad * 8];
      bf16x8 b2 = *(const bf16x8*)&Bs[2][wn + nf * 16 + lrow][lquad * 8];
#pragma unroll
      for (int mf = 0; mf < 4; mf++) {
        f32x4 c = acc[mf][nf];
        c = __builtin_amdgcn_mfma_f32_16x16x32_bf16(af[0][mf], b0, c, 0, 0, 0);
        c = __builtin_amdgcn_mfma_f32_16x16x32_bf16(af[0][mf], b1, c, 0, 0, 0);
        c = __builtin_amdgcn_mfma_f32_16x16x32_bf16(af[1][mf], b0, c, 0, 0, 0);
        c = __builtin_amdgcn_mfma_f32_16x16x32_bf16(af[0][mf], b2, c, 0, 0, 0);
        c = __builtin_amdgcn_mfma_f32_16x16x32_bf16(af[2][mf], b0, c, 0, 0, 0);
        c = __builtin_amdgcn_mfma_f32_16x16x32_bf16(af[1][mf], b1, c, 0, 0, 0);
        acc[mf][nf] = c;
      }
    }
  }
  // epilogue: C/D layout row=quad*4+r, col=lane&15
#pragma unroll
  for (int mf = 0; mf < 4; mf++) {
    int row0 = bm + wm + mf * 16 + lquad * 4;
#pragma unroll
    for (int nf = 0; nf < 4; nf++) {
      int colg = bn + wn + nf * 16 + lrow;
#pragma unroll
      for (int r = 0; r < 4; r++) {
        int row = row0 + r;
        if (row < M) C[(size_t)row * Nc + colg] = acc[mf][nf][r];
      }
    }
  }
}

// ---------------- alpha_src / alpha_dst per node (one wave per node) --------
template <int H>
__global__ void k_alpha(const float* __restrict__ h, const float* __restrict__ atts,
                        const float* __restrict__ attd, float* __restrict__ as_,
                        float* __restrict__ ad_) {
  int gid = blockIdx.x * blockDim.x + threadIdx.x;
  int node = gid >> 6, lane = gid & 63;
  if (node >= NN) return;
  constexpr int HF = H * 128, PL = HF / 64, G = 64 / H;
  const float* hp = h + (size_t)node * HF + lane * PL;
  float ps = 0.f, pd = 0.f;
#pragma unroll
  for (int i = 0; i < PL; i++) {
    int idx = lane * PL + i;
    float hv = hp[i];
    ps += hv * atts[idx];
    pd += hv * attd[idx];
  }
#pragma unroll
  for (int off = G >> 1; off; off >>= 1) {
    ps += __shfl_xor(ps, off, 64);
    pd += __shfl_xor(pd, off, 64);
  }
  if ((lane & (G - 1)) == 0) {
    int hh = lane / G;
    as_[node * H + hh] = ps;
    ad_[node * H + hh] = pd;
  }
}

// ---------------- softmax + aggregate (WPN waves per dst node) --------------
template <int H, int WPN, bool RELU>
__global__ __launch_bounds__(256) void k_agg(const float* __restrict__ h,
                                             const float* __restrict__ as_,
                                             const float* __restrict__ ad_,
                                             const int* __restrict__ row_ptr,
                                             const int* __restrict__ col,
                                             const float* __restrict__ bias,
                                             float* __restrict__ out) {
  int gid = blockIdx.x * blockDim.x + threadIdx.x;
  int gwid = gid >> 6, lane = gid & 63;
  int node = gwid / WPN, sub = gwid % WPN;
  if (node >= NN) return;
  constexpr int HF = H * 128, FPW = HF / WPN, PL = FPW / 64, HH = H / WPN;
  const int headbase = sub * HH;
  int beg = row_ptr[node], end = row_ptr[node + 1];

  float adv[HH], m[HH], s[HH];
#pragma unroll
  for (int i = 0; i < HH; i++) {
    adv[i] = ad_[node * H + headbase + i];
    m[i] = -1e30f;
    s[i] = 0.f;
  }
  // single online-softmax pass: per-lane running (m, s)
  for (int j = beg + lane; j < end; j += 64) {
    int sidx = col[j];
#pragma unroll
    for (int i = 0; i < HH; i++) {
      float e = as_[sidx * H + headbase + i] + adv[i];
      e = (e > 0.f) ? e : NEG * e;
      float nm = fmaxf(m[i], e);
      s[i] = s[i] * __expf(m[i] - nm) + __expf(e - nm);
      m[i] = nm;
    }
  }
  float Mred[HH], Sinv[HH];
#pragma unroll
  for (int i = 0; i < HH; i++) {
    float mm = m[i];
#pragma unroll
    for (int off = 32; off; off >>= 1) mm = fmaxf(mm, __shfl_xor(mm, off, 64));
    float term = s[i] * __expf(m[i] - mm);
#pragma unroll
    for (int off = 32; off; off >>= 1) term += __shfl_xor(term, off, 64);
    Mred[i] = mm;
    Sinv[i] = 1.f / term;
  }
  // weighted accumulate of h[src]
  int fbase = sub * FPW + lane * PL;
  int myh = fbase >> 7;
  int ih = myh - headbase;
  float mym = Mred[ih], myinv = Sinv[ih], myad = adv[ih];
  float acc[PL] = {};
  for (int j = beg; j < end; ++j) {
    int sidx = col[j];
    float e = as_[sidx * H + myh] + myad;
    e = (e > 0.f) ? e : NEG * e;
    float w = __expf(e - mym) * myinv;
    const float* hp = h + (size_t)sidx * HF + fbase;
    if constexpr (PL == 4) {
      float4 v = *(const float4*)hp;
      acc[0] += w * v.x;
      acc[1] += w * v.y;
      acc[2] += w * v.z;
      acc[3] += w * v.w;
    } else {
      float2 v = *(const float2*)hp;
      acc[0] += w * v.x;
      acc[1] += w * v.y;
    }
  }
  float* op = out + (size_t)node * HF + fbase;
#pragma unroll
  for (int i = 0; i < PL; i++) {
    float v = acc[i] + bias[fbase + i];
    if (RELU) v = fmaxf(v, 0.f);
    op[i] = v;
  }
}

// ---------------- masked global max pool ----------------
__global__ void k_pool(const float* __restrict__ h, const int* __restrict__ batch,
                       const int* __restrict__ mask, const int* __restrict__ flag,
                       unsigned* __restrict__ enc) {
  int f = threadIdx.x;  // 128 threads = 128 features
  int n0 = blockIdx.x * 32;
  if (n0 >= NN) return;
  int n1 = min(NN, n0 + 32);
  int any = *flag;
  float local = -1e30f;
  int curb = batch[n0];
  for (int n = n0; n < n1; ++n) {
    int b = batch[n];
    if (b != curb) {
      if (local > -1e30f) atomicMax(&enc[curb * 128 + f], encf(local));
      local = -1e30f;
      curb = b;
    }
    bool valid = (mask[n] == 0) || (!any);
    if (valid) local = fmaxf(local, h[(size_t)n * 128 + f]);
  }
  if (local > -1e30f) atomicMax(&enc[curb * 128 + f], encf(local));
}

__global__ void k_out(const unsigned* __restrict__ enc, float* __restrict__ out) {
  int i = blockIdx.x * blockDim.x + threadIdx.x;
  if (i < NBATCH * 128) out[i] = decf(enc[i]);
}

extern "C" void kernel_launch(void* const* d_in, const int* in_sizes, int n_in,
                              void* d_out, int out_size, void* d_ws, size_t ws_size,
                              hipStream_t stream) {
  const float* x = (const float*)d_in[0];
  const int* ei = (const int*)d_in[1];
  const int* batch = (const int*)d_in[2];
  const int* nmask = (const int*)d_in[3];
  // d_in[4] = edge_mask, unused
  const float* W1 = (const float*)d_in[5];
  const float* as1 = (const float*)d_in[6];
  const float* ad1 = (const float*)d_in[7];
  const float* b1 = (const float*)d_in[8];
  const float* W2 = (const float*)d_in[9];
  const float* as2 = (const float*)d_in[10];
  const float* ad2 = (const float*)d_in[11];
  const float* b2 = (const float*)d_in[12];
  const float* W3 = (const float*)d_in[13];
  const float* as3 = (const float*)d_in[14];
  const float* ad3 = (const float*)d_in[15];
  const float* b3 = (const float*)d_in[16];

  char* ws = (char*)d_ws;
  size_t off = 0;
  auto alloc = [&](size_t bytes) -> char* {
    char* p = ws + off;
    off = (off + bytes + 255) & ~(size_t)255;
    return p;
  };
  float* hA = (float*)alloc((size_t)NN * 512 * 4);
  float* hB = (float*)alloc((size_t)NN * 512 * 4);
  unsigned short* wt1 = (unsigned short*)alloc((size_t)3 * 512 * 128 * 2);
  unsigned short* wt2 = (unsigned short*)alloc((size_t)3 * 512 * 512 * 2);
  unsigned short* wt3 = (unsigned short*)alloc((size_t)3 * 128 * 512 * 2);
  float* alS = (float*)alloc((size_t)NN * 4 * 4);
  float* alD = (float*)alloc((size_t)NN * 4 * 4);
  int* deg = (int*)alloc((size_t)NN * 4);
  int* cursor = (int*)alloc((size_t)NN * 4);
  int* rowp = (int*)alloc((size_t)(NN + 1) * 4);
  int* colx = (int*)alloc((size_t)(NE + NN) * 4);
  unsigned* enc = (unsigned*)alloc((size_t)NBATCH * 128 * 4);
  int* flag = (int*)alloc(4);
  (void)ws_size; (void)n_in; (void)in_sizes; (void)out_size;

  hipMemsetAsync(flag, 0, 4, stream);
  k_init<<<(NN + 255) / 256, 256, 0, stream>>>(deg, enc);
  k_count<<<(NE + 255) / 256, 256, 0, stream>>>(ei, deg);
  k_scan<<<1, 1024, 0, stream>>>(deg, rowp, cursor);
  k_fill<<<(NE + NN + 255) / 256, 256, 0, stream>>>(ei, cursor, colx, nmask, flag);

  k_wprep<<<(512 * 128) / 256, 256, 0, stream>>>(W1, wt1, 128, 512, 9);
  k_wprep<<<(512 * 512) / 256, 256, 0, stream>>>(W2, wt2, 512, 512, 9);
  k_wprep<<<(128 * 512) / 256, 256, 0, stream>>>(W3, wt3, 512, 128, 7);

  dim3 gg1(512 / BN, (NN + BM - 1) / BM);
  dim3 gg3(128 / BN ? 128 / BN : 1, (NN + BM - 1) / BM);
  const int alphaBlocks = (NN * 64) / 256;

  // Layer 1
  k_gemm<<<gg1, 256, 0, stream>>>(x, wt1, hA, NN, 128, 512);
  k_alpha<4><<<alphaBlocks, 256, 0, stream>>>(hA, as1, ad1, alS, alD);
  k_agg<4, 2, true><<<(NN * 2 * 64) / 256, 256, 0, stream>>>(hA, alS, alD, rowp,
                                                             colx, b1, hB);
  // Layer 2
  k_gemm<<<gg1, 256, 0, stream>>>(hB, wt2, hA, NN, 512, 512);
  k_alpha<4><<<alphaBlocks, 256, 0, stream>>>(hA, as2, ad2, alS, alD);
  k_agg<4, 2, true><<<(NN * 2 * 64) / 256, 256, 0, stream>>>(hA, alS, alD, rowp,
                                                             colx, b2, hB);
  // Layer 3
  k_gemm<<<gg3, 256, 0, stream>>>(hB, wt3, hA, NN, 512, 128);
  k_alpha<1><<<alphaBlocks, 256, 0, stream>>>(hA, as3, ad3, alS, alD);
  k_agg<1, 1, false><<<(NN * 64) / 256, 256, 0, stream>>>(hA, alS, alD, rowp, colx,
                                                          b3, hB);

  // Masked global max pool
  k_pool<<<(NN + 31) / 32, 128, 0, stream>>>(hB, batch, nmask, flag, enc);
  k_out<<<(NBATCH * 128 + 255) / 256, 256, 0, stream>>>(enc, (float*)d_out);
}

// Round 5
// 621.371 us; speedup vs baseline: 1.1130x; 1.0003x over previous
//
#include <hip/hip_runtime.h>
#include <stdint.h>

// GAT encoder: 3 GAT layers + masked global max pool. fp32 pipeline.
// GEMMs on the bf16 matrix pipe via bf16x6 error-compensated split.
// alpha dots fused into GEMM epilogue (fp32 atomics).
// k_agg: chunked per-edge weights in wave-private LDS + unrolled gathers.

#define NN 20000
#define NE 320000
#define NBATCH 16
#define NEG 0.2f

using bf16x8 = __attribute__((ext_vector_type(8))) __bf16;
using f32x4 = __attribute__((ext_vector_type(4))) float;

static __device__ __forceinline__ unsigned short f2bf(float f) {  // RNE
  unsigned u = __float_as_uint(f);
  return (unsigned short)((u + 0x7FFFu + ((u >> 16) & 1u)) >> 16);
}
static __device__ __forceinline__ unsigned encf(float f) {
  unsigned u = __float_as_uint(f);
  return (u & 0x80000000u) ? ~u : (u | 0x80000000u);
}
static __device__ __forceinline__ float decf(unsigned u) {
  return __uint_as_float((u & 0x80000000u) ? (u ^ 0x80000000u) : ~u);
}

struct S3 { unsigned short h, m, l; };
static __device__ __forceinline__ S3 split3(float a) {
  unsigned u = __float_as_uint(a);
  unsigned hi = u & 0xFFFF0000u;
  float r = a - __uint_as_float(hi);  // exact
  unsigned ur = __float_as_uint(r);
  unsigned mi = ur & 0xFFFF0000u;
  float r2 = r - __uint_as_float(mi);  // exact
  S3 o;
  o.h = (unsigned short)(hi >> 16);
  o.m = (unsigned short)(mi >> 16);
  o.l = f2bf(r2);
  return o;
}

// ---------------- init + CSR build ----------------
__global__ void k_init(int* deg, unsigned* enc) {
  int i = blockIdx.x * blockDim.x + threadIdx.x;
  if (i < NN) deg[i] = 1;  // self loop
  if (i < NBATCH * 128) enc[i] = ~__float_as_uint(-1e30f);  // encf(-1e30)
}

__global__ void k_count(const int* __restrict__ ei, int* __restrict__ deg) {
  int e = blockIdx.x * blockDim.x + threadIdx.x;
  if (e < NE) atomicAdd(&deg[ei[NE + e]], 1);
}

__global__ void k_scan(const int* __restrict__ deg, int* __restrict__ row_ptr,
                       int* __restrict__ cursor) {
  __shared__ int wsum[16];
  int t = threadIdx.x;  // 1024 threads
  int lane = t & 63, wid = t >> 6;
  const int CH = 20;
  int beg = t * CH;
  int s = 0;
  for (int i = 0; i < CH; i++) {
    int idx = beg + i;
    if (idx < NN) s += deg[idx];
  }
  int incl = s;
  for (int off = 1; off < 64; off <<= 1) {
    int v = __shfl_up(incl, off, 64);
    if (lane >= off) incl += v;
  }
  if (lane == 63) wsum[wid] = incl;
  __syncthreads();
  if (t < 16) {
    int v = wsum[t];
    int in2 = v;
    for (int off = 1; off < 16; off <<= 1) {
      int u = __shfl_up(in2, off, 16);
      if (t >= off) in2 += u;
    }
    wsum[t] = in2 - v;  // exclusive wave base
  }
  __syncthreads();
  int run = wsum[wid] + incl - s;
  for (int i = 0; i < CH; i++) {
    int idx = beg + i;
    if (idx < NN) {
      row_ptr[idx] = run;
      cursor[idx] = run;
      run += deg[idx];
    }
  }
  if (t == 1023) row_ptr[NN] = run;
}

__global__ void k_fill(const int* __restrict__ ei, int* __restrict__ cursor,
                       int* __restrict__ col, const int* __restrict__ nmask,
                       int* __restrict__ flag) {
  int i = blockIdx.x * blockDim.x + threadIdx.x;
  if (i >= NE + NN) return;
  int src, dst;
  if (i < NE) {
    src = ei[i];
    dst = ei[NE + i];
  } else {
    src = dst = i - NE;
    if (nmask[src] != 0) *flag = 1;  // flag pre-zeroed by memsetAsync
  }
  int pos = atomicAdd(&cursor[dst], 1);
  col[pos] = src;
}

// ---------------- W prep: transpose + bf16x3 split ----------------
__global__ void k_wprep(const float* __restrict__ W, unsigned short* __restrict__ wt,
                        int K, int Nc, int ncshift) {
  int idx = blockIdx.x * blockDim.x + threadIdx.x;
  int n = idx & (Nc - 1);
  int k = idx >> ncshift;
  float a = W[(size_t)k * Nc + n];
  S3 s = split3(a);
  size_t pw = (size_t)Nc * K;
  size_t o = (size_t)n * K + k;
  wt[o] = s.h;
  wt[pw + o] = s.m;
  wt[2 * pw + o] = s.l;
}

// ---------------- GEMM via bf16x6 MFMA, fused alpha epilogue ----------------
#define BM 128
#define BN 128
#define BK 32

__global__ __launch_bounds__(256, 2) void k_gemm(
    const float* __restrict__ A, const unsigned short* __restrict__ Wt,
    float* __restrict__ C, const float* __restrict__ attS,
    const float* __restrict__ attD, float* __restrict__ alS,
    float* __restrict__ alD, int M, int K, int Nc, int H) {
  __shared__ __align__(16) unsigned short As[3][BM][BK];  // 24 KB
  __shared__ __align__(16) unsigned short Bs[3][BN][BK];  // 24 KB
  int tid = threadIdx.x;
  int bm = blockIdx.y * BM, bn = blockIdx.x * BN;
  int wid = tid >> 6, lane = tid & 63;
  int wm = (wid >> 1) * 64, wn = (wid & 1) * 64;
  int lrow = lane & 15, lquad = lane >> 4;
  size_t planeW = (size_t)Nc * K;

  f32x4 acc[4][4] = {};

  for (int k0 = 0; k0 < K; k0 += BK) {
    __syncthreads();
#pragma unroll
    for (int i = 0; i < 4; i++) {
      int slot = tid + 256 * i;  // 1024 float4 slots
      int row = slot >> 3;
      int kf = (slot & 7) * 4;
      int arow = bm + row;
      arow = arow < M ? arow : M - 1;
      float4 v = *(const float4*)(A + (size_t)arow * K + k0 + kf);
      S3 s0 = split3(v.x), s1 = split3(v.y), s2 = split3(v.z), s3 = split3(v.w);
      *(ushort4*)&As[0][row][kf] = make_ushort4(s0.h, s1.h, s2.h, s3.h);
      *(ushort4*)&As[1][row][kf] = make_ushort4(s0.m, s1.m, s2.m, s3.m);
      *(ushort4*)&As[2][row][kf] = make_ushort4(s0.l, s1.l, s2.l, s3.l);
    }
#pragma unroll
    for (int p = 0; p < 3; p++)
#pragma unroll
      for (int i = 0; i < 2; i++) {
        int slot = tid + 256 * i;  // 512 uint4 slots per plane
        int row = slot >> 2;
        int ks = (slot & 3) * 8;
        uint4 v = *(const uint4*)(Wt + (size_t)p * planeW + (size_t)(bn + row) * K +
                                  k0 + ks);
        *(uint4*)&Bs[p][row][ks] = v;
      }
    __syncthreads();

    bf16x8 af[3][4];
#pragma unroll
    for (int p = 0; p < 3; p++)
#pragma unroll
      for (int mf = 0; mf < 4; mf++)
        af[p][mf] = *(const bf16x8*)&As[p][wm + mf * 16 + lrow][lquad * 8];
#pragma unroll
    for (int nf = 0; nf < 4; nf++) {
      bf16x8 b0 = *(const bf16x8*)&Bs[0][wn + nf * 16 + lrow][lquad * 8];
      bf16x8 b1 = *(const bf16x8*)&Bs[1][wn + nf * 16 + lrow][lquad * 8];
      bf16x8 b2 = *(const bf16x8*)&Bs[2][wn + nf * 16 + lrow][lquad * 8];
#pragma unroll
      for (int mf = 0; mf < 4; mf++) {
        f32x4 c = acc[mf][nf];
        c = __builtin_amdgcn_mfma_f32_16x16x32_bf16(af[0][mf], b0, c, 0, 0, 0);
        c = __builtin_amdgcn_mfma_f32_16x16x32_bf16(af[0][mf], b1, c, 0, 0, 0);
        c = __builtin_amdgcn_mfma_f32_16x16x32_bf16(af[1][mf], b0, c, 0, 0, 0);
        c = __builtin_amdgcn_mfma_f32_16x16x32_bf16(af[0][mf], b2, c, 0, 0, 0);
        c = __builtin_amdgcn_mfma_f32_16x16x32_bf16(af[2][mf], b0, c, 0, 0, 0);
        c = __builtin_amdgcn_mfma_f32_16x16x32_bf16(af[1][mf], b1, c, 0, 0, 0);
        acc[mf][nf] = c;
      }
    }
  }
  // C store (C/D layout: row=quad*4+r, col=lane&15)
#pragma unroll
  for (int mf = 0; mf < 4; mf++) {
    int row0 = bm + wm + mf * 16 + lquad * 4;
#pragma unroll
    for (int nf = 0; nf < 4; nf++) {
      int colg = bn + wn + nf * 16 + lrow;
#pragma unroll
      for (int r = 0; r < 4; r++) {
        int row = row0 + r;
        if (row < M) C[(size_t)row * Nc + colg] = acc[mf][nf][r];
      }
    }
  }
  // fused alpha: this block's 128 cols == exactly one head
  float aSv[4], aDv[4];
#pragma unroll
  for (int nf = 0; nf < 4; nf++) {
    int colg = bn + wn + nf * 16 + lrow;
    aSv[nf] = attS[colg];
    aDv[nf] = attD[colg];
  }
  int head = bn >> 7;
#pragma unroll
  for (int mf = 0; mf < 4; mf++) {
#pragma unroll
    for (int r = 0; r < 4; r++) {
      float ps = 0.f, pd = 0.f;
#pragma unroll
      for (int nf = 0; nf < 4; nf++) {
        ps += acc[mf][nf][r] * aSv[nf];
        pd += acc[mf][nf][r] * aDv[nf];
      }
#pragma unroll
      for (int off = 1; off < 16; off <<= 1) {  // reduce the 16 lrow lanes
        ps += __shfl_xor(ps, off, 64);
        pd += __shfl_xor(pd, off, 64);
      }
      int row = bm + wm + mf * 16 + lquad * 4 + r;
      if (lrow == 0 && row < M) {
        atomicAdd(&alS[(size_t)row * H + head], ps);
        atomicAdd(&alD[(size_t)row * H + head], pd);
      }
    }
  }
}

// ---------------- softmax + aggregate (WPN waves per dst node) --------------
// Per 64-edge chunk: lane-parallel weight computation into wave-private LDS,
// then unrolled broadcast+gather accumulate (no barriers: wave-synchronous).
template <int H, int WPN, bool RELU>
__global__ __launch_bounds__(256) void k_agg(const float* __restrict__ h,
                                             const float* __restrict__ as_,
                                             const float* __restrict__ ad_,
                                             const int* __restrict__ row_ptr,
                                             const int* __restrict__ col,
                                             const float* __restrict__ bias,
                                             float* __restrict__ out) {
  constexpr int HF = H * 128, FPW = HF / WPN, PL = FPW / 64, HH = H / WPN;
  __shared__ float wl[4][HH][64];
  __shared__ int cl[4][64];
  int tid = threadIdx.x, bwid = tid >> 6, lane = tid & 63;
  int gwid = blockIdx.x * 4 + bwid;
  int node = gwid / WPN, sub = gwid % WPN;
  if (node >= NN) return;
  const int hb = sub * HH;
  int beg = row_ptr[node], end = row_ptr[node + 1];

  float adv[HH], m[HH], s[HH];
#pragma unroll
  for (int i = 0; i < HH; i++) {
    adv[i] = ad_[node * H + hb + i];
    m[i] = -1e30f;
    s[i] = 0.f;
  }
  // phase 1: online (m, s) per head, lane-parallel over edges
  for (int j = beg + lane; j < end; j += 64) {
    int sidx = col[j];
#pragma unroll
    for (int i = 0; i < HH; i++) {
      float e = as_[sidx * H + hb + i] + adv[i];
      e = (e > 0.f) ? e : NEG * e;
      float nm = fmaxf(m[i], e);
      s[i] = s[i] * __expf(m[i] - nm) + __expf(e - nm);
      m[i] = nm;
    }
  }
  float Mr[HH], Sinv[HH];
#pragma unroll
  for (int i = 0; i < HH; i++) {
    float mm = m[i];
#pragma unroll
    for (int off = 32; off; off >>= 1) mm = fmaxf(mm, __shfl_xor(mm, off, 64));
    float t = s[i] * __expf(m[i] - mm);
#pragma unroll
    for (int off = 32; off; off >>= 1) t += __shfl_xor(t, off, 64);
    Mr[i] = mm;
    Sinv[i] = 1.f / t;
  }
  // phase 2: chunked weights -> LDS, unrolled gather-accumulate
  const int fbase = sub * FPW + lane * PL;
  const int ih = (lane * PL) >> 7;  // which of this wave's HH heads
  float acc[PL] = {};
  for (int c0 = beg; c0 < end; c0 += 64) {
    int cnt = min(64, end - c0);
    if (lane < cnt) {
      int sidx = col[c0 + lane];
      cl[bwid][lane] = sidx;
#pragma unroll
      for (int i = 0; i < HH; i++) {
        float e = as_[sidx * H + hb + i] + adv[i];
        e = (e > 0.f) ? e : NEG * e;
        wl[bwid][i][lane] = __expf(e - Mr[i]) * Sinv[i];
      }
    }
    constexpr int UN = (PL == 2) ? 8 : 4;
    for (int je = 0; je < cnt; je += UN) {
      float wv[UN];
      int sv[UN];
#pragma unroll
      for (int r = 0; r < UN; r++) {
        int ok = (je + r) < cnt;
        int idx = ok ? (je + r) : 0;
        sv[r] = cl[bwid][idx];
        wv[r] = ok ? wl[bwid][ih][idx] : 0.f;
      }
      if constexpr (PL == 4) {
        float4 v[UN];
#pragma unroll
        for (int r = 0; r < UN; r++)
          v[r] = *(const float4*)(h + (size_t)sv[r] * HF + fbase);
#pragma unroll
        for (int r = 0; r < UN; r++) {
          acc[0] += wv[r] * v[r].x;
          acc[1] += wv[r] * v[r].y;
          acc[2] += wv[r] * v[r].z;
          acc[3] += wv[r] * v[r].w;
        }
      } else {
        float2 v[UN];
#pragma unroll
        for (int r = 0; r < UN; r++)
          v[r] = *(const float2*)(h + (size_t)sv[r] * HF + fbase);
#pragma unroll
        for (int r = 0; r < UN; r++) {
          acc[0] += wv[r] * v[r].x;
          acc[1] += wv[r] * v[r].y;
        }
      }
    }
  }
  float* op = out + (size_t)node * HF + fbase;
#pragma unroll
  for (int i = 0; i < PL; i++) {
    float v = acc[i] + bias[fbase + i];
    if (RELU) v = fmaxf(v, 0.f);
    op[i] = v;
  }
}

// ---------------- masked global max pool ----------------
__global__ void k_pool(const float* __restrict__ h, const int* __restrict__ batch,
                       const int* __restrict__ mask, const int* __restrict__ flag,
                       unsigned* __restrict__ enc) {
  int f = threadIdx.x;  // 128 threads = 128 features
  int n0 = blockIdx.x * 32;
  if (n0 >= NN) return;
  int n1 = min(NN, n0 + 32);
  int any = *flag;
  float local = -1e30f;
  int curb = batch[n0];
  for (int n = n0; n < n1; ++n) {
    int b = batch[n];
    if (b != curb) {
      if (local > -1e30f) atomicMax(&enc[curb * 128 + f], encf(local));
      local = -1e30f;
      curb = b;
    }
    bool valid = (mask[n] == 0) || (!any);
    if (valid) local = fmaxf(local, h[(size_t)n * 128 + f]);
  }
  if (local > -1e30f) atomicMax(&enc[curb * 128 + f], encf(local));
}

__global__ void k_out(const unsigned* __restrict__ enc, float* __restrict__ out) {
  int i = blockIdx.x * blockDim.x + threadIdx.x;
  if (i < NBATCH * 128) out[i] = decf(enc[i]);
}

extern "C" void kernel_launch(void* const* d_in, const int* in_sizes, int n_in,
                              void* d_out, int out_size, void* d_ws, size_t ws_size,
                              hipStream_t stream) {
  const float* x = (const float*)d_in[0];
  const int* ei = (const int*)d_in[1];
  const int* batch = (const int*)d_in[2];
  const int* nmask = (const int*)d_in[3];
  // d_in[4] = edge_mask, unused
  const float* W1 = (const float*)d_in[5];
  const float* as1 = (const float*)d_in[6];
  const float* ad1 = (const float*)d_in[7];
  const float* b1 = (const float*)d_in[8];
  const float* W2 = (const float*)d_in[9];
  const float* as2 = (const float*)d_in[10];
  const float* ad2 = (const float*)d_in[11];
  const float* b2 = (const float*)d_in[12];
  const float* W3 = (const float*)d_in[13];
  const float* as3 = (const float*)d_in[14];
  const float* ad3 = (const float*)d_in[15];
  const float* b3 = (const float*)d_in[16];

  char* ws = (char*)d_ws;
  size_t off = 0;
  auto alloc = [&](size_t bytes) -> char* {
    char* p = ws + off;
    off = (off + bytes + 255) & ~(size_t)255;
    return p;
  };
  float* hA = (float*)alloc((size_t)NN * 512 * 4);
  float* hB = (float*)alloc((size_t)NN * 512 * 4);
  unsigned short* wt1 = (unsigned short*)alloc((size_t)3 * 512 * 128 * 2);
  unsigned short* wt2 = (unsigned short*)alloc((size_t)3 * 512 * 512 * 2);
  unsigned short* wt3 = (unsigned short*)alloc((size_t)3 * 128 * 512 * 2);
  char* alStart = ws + off;
  float* alS1 = (float*)alloc((size_t)NN * 4 * 4);
  float* alD1 = (float*)alloc((size_t)NN * 4 * 4);
  float* alS2 = (float*)alloc((size_t)NN * 4 * 4);
  float* alD2 = (float*)alloc((size_t)NN * 4 * 4);
  float* alS3 = (float*)alloc((size_t)NN * 4);
  float* alD3 = (float*)alloc((size_t)NN * 4);
  size_t alBytes = (size_t)((ws + off) - alStart);
  int* deg = (int*)alloc((size_t)NN * 4);
  int* cursor = (int*)alloc((size_t)NN * 4);
  int* rowp = (int*)alloc((size_t)(NN + 1) * 4);
  int* colx = (int*)alloc((size_t)(NE + NN) * 4);
  unsigned* enc = (unsigned*)alloc((size_t)NBATCH * 128 * 4);
  int* flag = (int*)alloc(4);
  (void)ws_size; (void)n_in; (void)in_sizes; (void)out_size;

  hipMemsetAsync(flag, 0, 4, stream);
  hipMemsetAsync(alStart, 0, alBytes, stream);
  k_init<<<(NN + 255) / 256, 256, 0, stream>>>(deg, enc);
  k_count<<<(NE + 255) / 256, 256, 0, stream>>>(ei, deg);
  k_scan<<<1, 1024, 0, stream>>>(deg, rowp, cursor);
  k_fill<<<(NE + NN + 255) / 256, 256, 0, stream>>>(ei, cursor, colx, nmask, flag);

  k_wprep<<<(512 * 128) / 256, 256, 0, stream>>>(W1, wt1, 128, 512, 9);
  k_wprep<<<(512 * 512) / 256, 256, 0, stream>>>(W2, wt2, 512, 512, 9);
  k_wprep<<<(128 * 512) / 256, 256, 0, stream>>>(W3, wt3, 512, 128, 7);

  dim3 gg1(512 / BN, (NN + BM - 1) / BM);
  dim3 gg3(1, (NN + BM - 1) / BM);

  // Layer 1
  k_gemm<<<gg1, 256, 0, stream>>>(x, wt1, hA, as1, ad1, alS1, alD1, NN, 128, 512, 4);
  k_agg<4, 2, true><<<(NN * 2 + 3) / 4, 256, 0, stream>>>(hA, alS1, alD1, rowp,
                                                          colx, b1, hB);
  // Layer 2
  k_gemm<<<gg1, 256, 0, stream>>>(hB, wt2, hA, as2, ad2, alS2, alD2, NN, 512, 512, 4);
  k_agg<4, 2, true><<<(NN * 2 + 3) / 4, 256, 0, stream>>>(hA, alS2, alD2, rowp,
                                                          colx, b2, hB);
  // Layer 3
  k_gemm<<<gg3, 256, 0, stream>>>(hB, wt3, hA, as3, ad3, alS3, alD3, NN, 512, 128, 1);
  k_agg<1, 1, false><<<(NN + 3) / 4, 256, 0, stream>>>(hA, alS3, alD3, rowp, colx,
                                                       b3, hB);

  // Masked global max pool
  k_pool<<<(NN + 31) / 32, 128, 0, stream>>>(hB, batch, nmask, flag, enc);
  k_out<<<(NBATCH * 128 + 255) / 256, 256, 0, stream>>>(enc, (float*)d_out);
}

// Round 6
// 526.901 us; speedup vs baseline: 1.3125x; 1.1793x over previous
//
#include <hip/hip_runtime.h>
#include <stdint.h>

// GAT encoder: 3 GAT layers + masked global max pool. fp32 pipeline.
// GEMMs on the f16 matrix pipe via fp16x3 error-compensated split
// (a=ah+am, b=bh+bm, terms hh+hm+mh; 11-bit mantissa products exact in fp32;
// W planes pre-scaled x64 to dodge fp16 subnormal flush, acc scaled back).
// alpha dots fused into GEMM epilogue (fp32 atomics).
// k_agg: 1 head per wave (WPN=4 for H=4), phase-1 e-values stashed in LDS.

#define NN 20000
#define NE 320000
#define NBATCH 16
#define NEG 0.2f
#define WSCALE 64.0f
#define WINV 0.015625f

using f16x8 = __attribute__((ext_vector_type(8))) _Float16;
using f32x4 = __attribute__((ext_vector_type(4))) float;

static __device__ __forceinline__ unsigned short h2u(_Float16 h) {
  union { _Float16 f; unsigned short u; } c;
  c.f = h;
  return c.u;
}
static __device__ __forceinline__ unsigned encf(float f) {
  unsigned u = __float_as_uint(f);
  return (u & 0x80000000u) ? ~u : (u | 0x80000000u);
}
static __device__ __forceinline__ float decf(unsigned u) {
  return __uint_as_float((u & 0x80000000u) ? (u ^ 0x80000000u) : ~u);
}

struct S2 { unsigned short h, m; };
static __device__ __forceinline__ S2 split2(float a) {
  _Float16 ah = (_Float16)a;
  float r = a - (float)ah;  // exact (Sterbenz)
  _Float16 am = (_Float16)r;
  S2 o;
  o.h = h2u(ah);
  o.m = h2u(am);
  return o;
}

// ---------------- init + CSR build ----------------
__global__ void k_init(int* deg, unsigned* enc) {
  int i = blockIdx.x * blockDim.x + threadIdx.x;
  if (i < NN) deg[i] = 1;  // self loop
  if (i < NBATCH * 128) enc[i] = ~__float_as_uint(-1e30f);  // encf(-1e30)
}

__global__ void k_count(const int* __restrict__ ei, int* __restrict__ deg) {
  int e = blockIdx.x * blockDim.x + threadIdx.x;
  if (e < NE) atomicAdd(&deg[ei[NE + e]], 1);
}

__global__ void k_scan(const int* __restrict__ deg, int* __restrict__ row_ptr,
                       int* __restrict__ cursor) {
  __shared__ int wsum[16];
  int t = threadIdx.x;  // 1024 threads
  int lane = t & 63, wid = t >> 6;
  const int CH = 20;
  int beg = t * CH;
  int s = 0;
  for (int i = 0; i < CH; i++) {
    int idx = beg + i;
    if (idx < NN) s += deg[idx];
  }
  int incl = s;
  for (int off = 1; off < 64; off <<= 1) {
    int v = __shfl_up(incl, off, 64);
    if (lane >= off) incl += v;
  }
  if (lane == 63) wsum[wid] = incl;
  __syncthreads();
  if (t < 16) {
    int v = wsum[t];
    int in2 = v;
    for (int off = 1; off < 16; off <<= 1) {
      int u = __shfl_up(in2, off, 16);
      if (t >= off) in2 += u;
    }
    wsum[t] = in2 - v;  // exclusive wave base
  }
  __syncthreads();
  int run = wsum[wid] + incl - s;
  for (int i = 0; i < CH; i++) {
    int idx = beg + i;
    if (idx < NN) {
      row_ptr[idx] = run;
      cursor[idx] = run;
      run += deg[idx];
    }
  }
  if (t == 1023) row_ptr[NN] = run;
}

__global__ void k_fill(const int* __restrict__ ei, int* __restrict__ cursor,
                       int* __restrict__ col, const int* __restrict__ nmask,
                       int* __restrict__ flag) {
  int i = blockIdx.x * blockDim.x + threadIdx.x;
  if (i >= NE + NN) return;
  int src, dst;
  if (i < NE) {
    src = ei[i];
    dst = ei[NE + i];
  } else {
    src = dst = i - NE;
    if (nmask[src] != 0) *flag = 1;  // flag pre-zeroed by memsetAsync
  }
  int pos = atomicAdd(&cursor[dst], 1);
  col[pos] = src;
}

// ---------------- W prep: transpose + x64 scale + fp16x2 split --------------
// in:  W [K][Nc] fp32; out: wt [2][Nc][K] fp16 (hi, lo planes, k-contiguous)
__global__ void k_wprep(const float* __restrict__ W, unsigned short* __restrict__ wt,
                        int K, int Nc, int ncshift) {
  int idx = blockIdx.x * blockDim.x + threadIdx.x;
  int n = idx & (Nc - 1);
  int k = idx >> ncshift;
  float a = W[(size_t)k * Nc + n] * WSCALE;
  S2 s = split2(a);
  size_t pw = (size_t)Nc * K;
  size_t o = (size_t)n * K + k;
  wt[o] = s.h;
  wt[pw + o] = s.m;
}

// ---------------- GEMM via fp16x3 MFMA, fused alpha epilogue ----------------
#define BM 128
#define BN 128
#define BK 32

__global__ __launch_bounds__(256, 2) void k_gemm(
    const float* __restrict__ A, const unsigned short* __restrict__ Wt,
    float* __restrict__ C, const float* __restrict__ attS,
    const float* __restrict__ attD, float* __restrict__ alS,
    float* __restrict__ alD, int M, int K, int Nc, int H) {
  __shared__ __align__(16) unsigned short As[2][BM][BK];  // 16 KB
  __shared__ __align__(16) unsigned short Bs[2][BN][BK];  // 16 KB
  int tid = threadIdx.x;
  int bm = blockIdx.y * BM, bn = blockIdx.x * BN;
  int wid = tid >> 6, lane = tid & 63;
  int wm = (wid >> 1) * 64, wn = (wid & 1) * 64;
  int lrow = lane & 15, lquad = lane >> 4;
  size_t planeW = (size_t)Nc * K;

  f32x4 acc[4][4] = {};

  for (int k0 = 0; k0 < K; k0 += BK) {
    __syncthreads();
    // stage A: 128x32 fp32 -> 2 fp16 planes (in-register split)
#pragma unroll
    for (int i = 0; i < 4; i++) {
      int slot = tid + 256 * i;  // 1024 float4 slots
      int row = slot >> 3;
      int kf = (slot & 7) * 4;
      int arow = bm + row;
      arow = arow < M ? arow : M - 1;
      float4 v = *(const float4*)(A + (size_t)arow * K + k0 + kf);
      S2 s0 = split2(v.x), s1 = split2(v.y), s2 = split2(v.z), s3 = split2(v.w);
      *(ushort4*)&As[0][row][kf] = make_ushort4(s0.h, s1.h, s2.h, s3.h);
      *(ushort4*)&As[1][row][kf] = make_ushort4(s0.m, s1.m, s2.m, s3.m);
    }
    // stage B: pre-split planes, straight copy
#pragma unroll
    for (int p = 0; p < 2; p++)
#pragma unroll
      for (int i = 0; i < 2; i++) {
        int slot = tid + 256 * i;  // 512 uint4 slots per plane
        int row = slot >> 2;
        int ks = (slot & 3) * 8;
        uint4 v = *(const uint4*)(Wt + (size_t)p * planeW + (size_t)(bn + row) * K +
                                  k0 + ks);
        *(uint4*)&Bs[p][row][ks] = v;
      }
    __syncthreads();

    f16x8 af[2][4];
#pragma unroll
    for (int p = 0; p < 2; p++)
#pragma unroll
      for (int mf = 0; mf < 4; mf++)
        af[p][mf] = *(const f16x8*)&As[p][wm + mf * 16 + lrow][lquad * 8];
#pragma unroll
    for (int nf = 0; nf < 4; nf++) {
      f16x8 bh = *(const f16x8*)&Bs[0][wn + nf * 16 + lrow][lquad * 8];
      f16x8 bl = *(const f16x8*)&Bs[1][wn + nf * 16 + lrow][lquad * 8];
#pragma unroll
      for (int mf = 0; mf < 4; mf++) {
        f32x4 c = acc[mf][nf];
        c = __builtin_amdgcn_mfma_f32_16x16x32_f16(af[1][mf], bh, c, 0, 0, 0);
        c = __builtin_amdgcn_mfma_f32_16x16x32_f16(af[0][mf], bl, c, 0, 0, 0);
        c = __builtin_amdgcn_mfma_f32_16x16x32_f16(af[0][mf], bh, c, 0, 0, 0);
        acc[mf][nf] = c;
      }
    }
  }
  // undo the x64 W scale
#pragma unroll
  for (int mf = 0; mf < 4; mf++)
#pragma unroll
    for (int nf = 0; nf < 4; nf++)
#pragma unroll
      for (int r = 0; r < 4; r++) acc[mf][nf][r] *= WINV;
  // C store (C/D layout: row=quad*4+r, col=lane&15)
#pragma unroll
  for (int mf = 0; mf < 4; mf++) {
    int row0 = bm + wm + mf * 16 + lquad * 4;
#pragma unroll
    for (int nf = 0; nf < 4; nf++) {
      int colg = bn + wn + nf * 16 + lrow;
#pragma unroll
      for (int r = 0; r < 4; r++) {
        int row = row0 + r;
        if (row < M) C[(size_t)row * Nc + colg] = acc[mf][nf][r];
      }
    }
  }
  // fused alpha: this block's 128 cols == exactly one head
  float aSv[4], aDv[4];
#pragma unroll
  for (int nf = 0; nf < 4; nf++) {
    int colg = bn + wn + nf * 16 + lrow;
    aSv[nf] = attS[colg];
    aDv[nf] = attD[colg];
  }
  int head = bn >> 7;
#pragma unroll
  for (int mf = 0; mf < 4; mf++) {
#pragma unroll
    for (int r = 0; r < 4; r++) {
      float ps = 0.f, pd = 0.f;
#pragma unroll
      for (int nf = 0; nf < 4; nf++) {
        ps += acc[mf][nf][r] * aSv[nf];
        pd += acc[mf][nf][r] * aDv[nf];
      }
#pragma unroll
      for (int off = 1; off < 16; off <<= 1) {  // reduce the 16 lrow lanes
        ps += __shfl_xor(ps, off, 64);
        pd += __shfl_xor(pd, off, 64);
      }
      int row = bm + wm + mf * 16 + lquad * 4 + r;
      if (lrow == 0 && row < M) {
        atomicAdd(&alS[(size_t)row * H + head], ps);
        atomicAdd(&alD[(size_t)row * H + head], pd);
      }
    }
  }
}

// ---------------- softmax + aggregate (WPN waves per dst node) --------------
// Phase 1 stashes post-leaky e in LDS (valid when deg<=64: the common case),
// so phase 2 needs no scattered re-gather. Wave-synchronous, no barriers.
template <int H, int WPN, bool RELU>
__global__ __launch_bounds__(256) void k_agg(const float* __restrict__ h,
                                             const float* __restrict__ as_,
                                             const float* __restrict__ ad_,
                                             const int* __restrict__ row_ptr,
                                             const int* __restrict__ col,
                                             const float* __restrict__ bias,
                                             float* __restrict__ out) {
  constexpr int HF = H * 128, FPW = HF / WPN, PL = FPW / 64, HH = H / WPN;
  static_assert(PL == 2, "one float2 per lane");
  __shared__ float el[4][HH][64];
  __shared__ float wl[4][HH][64];
  __shared__ int cl[4][64];
  int tid = threadIdx.x, bwid = tid >> 6, lane = tid & 63;
  int gwid = blockIdx.x * 4 + bwid;
  int node = gwid / WPN, sub = gwid - node * WPN;
  if (node >= NN) return;
  const int hb = sub * HH;
  int beg = row_ptr[node], end = row_ptr[node + 1];
  int deg = end - beg;

  float adv[HH], m[HH], s[HH];
#pragma unroll
  for (int i = 0; i < HH; i++) {
    adv[i] = ad_[node * H + hb + i];
    m[i] = -1e30f;
    s[i] = 0.f;
  }
  // phase 1: online (m, s); stash e + col in wave LDS
  for (int j = beg + lane; j < end; j += 64) {
    int sidx = col[j];
    cl[bwid][lane] = sidx;
#pragma unroll
    for (int i = 0; i < HH; i++) {
      float e = as_[sidx * H + hb + i] + adv[i];
      e = (e > 0.f) ? e : NEG * e;
      el[bwid][i][lane] = e;
      float nm = fmaxf(m[i], e);
      s[i] = s[i] * __expf(m[i] - nm) + __expf(e - nm);
      m[i] = nm;
    }
  }
  float Mr[HH], Sinv[HH];
#pragma unroll
  for (int i = 0; i < HH; i++) {
    float mm = m[i];
#pragma unroll
    for (int off = 32; off; off >>= 1) mm = fmaxf(mm, __shfl_xor(mm, off, 64));
    float t = s[i] * __expf(m[i] - mm);
#pragma unroll
    for (int off = 32; off; off >>= 1) t += __shfl_xor(t, off, 64);
    Mr[i] = mm;
    Sinv[i] = 1.f / t;
  }
  // phase 2: weights from stashed e (deg<=64) or re-gather (rare), then
  // broadcast+gather accumulate with 8 loads in flight
  const int fbase = sub * FPW + lane * PL;
  const int ih = (lane * PL) >> 7;  // 0..HH-1
  float acc0 = 0.f, acc1 = 0.f;
  for (int c0 = beg; c0 < end; c0 += 64) {
    int cnt = min(64, end - c0);
    if (deg <= 64) {
      if (lane < cnt) {
#pragma unroll
        for (int i = 0; i < HH; i++)
          wl[bwid][i][lane] = __expf(el[bwid][i][lane] - Mr[i]) * Sinv[i];
      }
    } else {
      if (lane < cnt) {
        int sidx = col[c0 + lane];
        cl[bwid][lane] = sidx;
#pragma unroll
        for (int i = 0; i < HH; i++) {
          float e = as_[sidx * H + hb + i] + adv[i];
          e = (e > 0.f) ? e : NEG * e;
          wl[bwid][i][lane] = __expf(e - Mr[i]) * Sinv[i];
        }
      }
    }
    for (int je = 0; je < cnt; je += 8) {
      float wv[8];
      int sv[8];
#pragma unroll
      for (int r = 0; r < 8; r++) {
        int ok = (je + r) < cnt;
        int idx = ok ? (je + r) : 0;
        sv[r] = cl[bwid][idx];
        wv[r] = ok ? wl[bwid][ih][idx] : 0.f;
      }
      float2 v[8];
#pragma unroll
      for (int r = 0; r < 8; r++)
        v[r] = *(const float2*)(h + (size_t)sv[r] * HF + fbase);
#pragma unroll
      for (int r = 0; r < 8; r++) {
        acc0 += wv[r] * v[r].x;
        acc1 += wv[r] * v[r].y;
      }
    }
  }
  float* op = out + (size_t)node * HF + fbase;
  float v0 = acc0 + bias[fbase], v1 = acc1 + bias[fbase + 1];
  if (RELU) {
    v0 = fmaxf(v0, 0.f);
    v1 = fmaxf(v1, 0.f);
  }
  op[0] = v0;
  op[1] = v1;
}

// ---------------- masked global max pool ----------------
__global__ void k_pool(const float* __restrict__ h, const int* __restrict__ batch,
                       const int* __restrict__ mask, const int* __restrict__ flag,
                       unsigned* __restrict__ enc) {
  int f = threadIdx.x;  // 128 threads = 128 features
  int n0 = blockIdx.x * 32;
  if (n0 >= NN) return;
  int n1 = min(NN, n0 + 32);
  int any = *flag;
  float local = -1e30f;
  int curb = batch[n0];
  for (int n = n0; n < n1; ++n) {
    int b = batch[n];
    if (b != curb) {
      if (local > -1e30f) atomicMax(&enc[curb * 128 + f], encf(local));
      local = -1e30f;
      curb = b;
    }
    bool valid = (mask[n] == 0) || (!any);
    if (valid) local = fmaxf(local, h[(size_t)n * 128 + f]);
  }
  if (local > -1e30f) atomicMax(&enc[curb * 128 + f], encf(local));
}

__global__ void k_out(const unsigned* __restrict__ enc, float* __restrict__ out) {
  int i = blockIdx.x * blockDim.x + threadIdx.x;
  if (i < NBATCH * 128) out[i] = decf(enc[i]);
}

extern "C" void kernel_launch(void* const* d_in, const int* in_sizes, int n_in,
                              void* d_out, int out_size, void* d_ws, size_t ws_size,
                              hipStream_t stream) {
  const float* x = (const float*)d_in[0];
  const int* ei = (const int*)d_in[1];
  const int* batch = (const int*)d_in[2];
  const int* nmask = (const int*)d_in[3];
  // d_in[4] = edge_mask, unused
  const float* W1 = (const float*)d_in[5];
  const float* as1 = (const float*)d_in[6];
  const float* ad1 = (const float*)d_in[7];
  const float* b1 = (const float*)d_in[8];
  const float* W2 = (const float*)d_in[9];
  const float* as2 = (const float*)d_in[10];
  const float* ad2 = (const float*)d_in[11];
  const float* b2 = (const float*)d_in[12];
  const float* W3 = (const float*)d_in[13];
  const float* as3 = (const float*)d_in[14];
  const float* ad3 = (const float*)d_in[15];
  const float* b3 = (const float*)d_in[16];

  char* ws = (char*)d_ws;
  size_t off = 0;
  auto alloc = [&](size_t bytes) -> char* {
    char* p = ws + off;
    off = (off + bytes + 255) & ~(size_t)255;
    return p;
  };
  float* hA = (float*)alloc((size_t)NN * 512 * 4);
  float* hB = (float*)alloc((size_t)NN * 512 * 4);
  unsigned short* wt1 = (unsigned short*)alloc((size_t)2 * 512 * 128 * 2);
  unsigned short* wt2 = (unsigned short*)alloc((size_t)2 * 512 * 512 * 2);
  unsigned short* wt3 = (unsigned short*)alloc((size_t)2 * 128 * 512 * 2);
  char* alStart = ws + off;
  float* alS1 = (float*)alloc((size_t)NN * 4 * 4);
  float* alD1 = (float*)alloc((size_t)NN * 4 * 4);
  float* alS2 = (float*)alloc((size_t)NN * 4 * 4);
  float* alD2 = (float*)alloc((size_t)NN * 4 * 4);
  float* alS3 = (float*)alloc((size_t)NN * 4);
  float* alD3 = (float*)alloc((size_t)NN * 4);
  size_t alBytes = (size_t)((ws + off) - alStart);
  int* deg = (int*)alloc((size_t)NN * 4);
  int* cursor = (int*)alloc((size_t)NN * 4);
  int* rowp = (int*)alloc((size_t)(NN + 1) * 4);
  int* colx = (int*)alloc((size_t)(NE + NN) * 4);
  unsigned* enc = (unsigned*)alloc((size_t)NBATCH * 128 * 4);
  int* flag = (int*)alloc(4);
  (void)ws_size; (void)n_in; (void)in_sizes; (void)out_size;

  hipMemsetAsync(flag, 0, 4, stream);
  hipMemsetAsync(alStart, 0, alBytes, stream);
  k_init<<<(NN + 255) / 256, 256, 0, stream>>>(deg, enc);
  k_count<<<(NE + 255) / 256, 256, 0, stream>>>(ei, deg);
  k_scan<<<1, 1024, 0, stream>>>(deg, rowp, cursor);
  k_fill<<<(NE + NN + 255) / 256, 256, 0, stream>>>(ei, cursor, colx, nmask, flag);

  k_wprep<<<(512 * 128) / 256, 256, 0, stream>>>(W1, wt1, 128, 512, 9);
  k_wprep<<<(512 * 512) / 256, 256, 0, stream>>>(W2, wt2, 512, 512, 9);
  k_wprep<<<(128 * 512) / 256, 256, 0, stream>>>(W3, wt3, 512, 128, 7);

  dim3 gg1(512 / BN, (NN + BM - 1) / BM);
  dim3 gg3(1, (NN + BM - 1) / BM);

  // Layer 1
  k_gemm<<<gg1, 256, 0, stream>>>(x, wt1, hA, as1, ad1, alS1, alD1, NN, 128, 512, 4);
  k_agg<4, 4, true><<<NN, 256, 0, stream>>>(hA, alS1, alD1, rowp, colx, b1, hB);
  // Layer 2
  k_gemm<<<gg1, 256, 0, stream>>>(hB, wt2, hA, as2, ad2, alS2, alD2, NN, 512, 512, 4);
  k_agg<4, 4, true><<<NN, 256, 0, stream>>>(hA, alS2, alD2, rowp, colx, b2, hB);
  // Layer 3
  k_gemm<<<gg3, 256, 0, stream>>>(hB, wt3, hA, as3, ad3, alS3, alD3, NN, 512, 128, 1);
  k_agg<1, 1, false><<<(NN + 3) / 4, 256, 0, stream>>>(hA, alS3, alD3, rowp, colx,
                                                       b3, hB);

  // Masked global max pool
  k_pool<<<(NN + 31) / 32, 128, 0, stream>>>(hB, batch, nmask, flag, enc);
  k_out<<<(NBATCH * 128 + 255) / 256, 256, 0, stream>>>(enc, (float*)d_out);
}